// Round 1
// baseline (443.625 us; speedup 1.0000x reference)
//
#include <hip/hip_runtime.h>

// LoRA forward: out = (h @ B^T) @ A^T, h: (16384, 4096) f32, rank 16.
// Fused single kernel. Tile = 64 rows per block, 1024 threads (16 waves).
// Stage 1: lane<->row mapping so B addresses are wave-uniform -> scalar loads.
// Stage 2: per-thread A fragment in VGPRs, hr broadcast from LDS, coalesced
// float4 stores.

constexpr int D_EMBED  = 4096;
constexpr int RANK     = 16;
constexpr int TILE_ROWS = 64;
constexpr int NWAVES   = 16;                  // 1024 threads
constexpr int DCHUNK   = D_EMBED / NWAVES;    // 256

__device__ __forceinline__ float dot4(float4 a, float4 b) {
  return a.x * b.x + a.y * b.y + a.z * b.z + a.w * b.w;
}

__global__ __launch_bounds__(1024) void lora_fused_kernel(
    const float* __restrict__ h,
    const float* __restrict__ matA,   // (D_EMBED, RANK) row-major
    const float* __restrict__ matB,   // (RANK, D_EMBED) row-major
    float* __restrict__ out) {
  // [wave][r][row] so stage-1 writes and reduce reads are stride-1 per wave.
  __shared__ float hrp[NWAVES][RANK][TILE_ROWS];  // 64 KiB
  __shared__ float hr[TILE_ROWS][RANK];           // 4 KiB

  const int tid  = threadIdx.x;
  const int wave = tid >> 6;
  const int lane = tid & 63;
  const long row0 = (long)blockIdx.x * TILE_ROWS;

  // ---------------- Stage 1: hr partials (lane owns one row) ----------------
  {
    // wave*DCHUNK is wave-uniform; readfirstlane pins it to an SGPR so the
    // B loads below are provably uniform -> s_load (scalar cache), not VMEM.
    const int d0 = __builtin_amdgcn_readfirstlane(wave * DCHUNK);
    const float* hp = h + (row0 + lane) * D_EMBED + d0;
    const float* bp = matB + d0;

    float acc[RANK];
#pragma unroll
    for (int r = 0; r < RANK; ++r) acc[r] = 0.f;

#pragma unroll 4
    for (int i = 0; i < DCHUNK; i += 4) {
      const float4 hv = *reinterpret_cast<const float4*>(hp + i);
#pragma unroll
      for (int r = 0; r < RANK; ++r) {
        const float4 bv =
            *reinterpret_cast<const float4*>(bp + r * D_EMBED + i);
        acc[r] += dot4(hv, bv);
      }
    }

#pragma unroll
    for (int r = 0; r < RANK; ++r) hrp[wave][r][lane] = acc[r];  // stride-1
  }
  __syncthreads();

  // ---------------- Reduce the 16 per-wave partials ----------------
  {
    // thread (wave, lane) handles entry (row=lane, r=wave): stride-1 reads.
    float s = 0.f;
#pragma unroll
    for (int w = 0; w < NWAVES; ++w) s += hrp[w][wave][lane];
    hr[lane][wave] = s;  // one-time write, conflict cost negligible
  }
  __syncthreads();

  // ---------------- Stage 2: out[row][c] = sum_r hr[row][r] * A[c][r] ------
  {
    const int c0 = tid * 4;  // 4 contiguous columns per thread; block = 4096
    float4 a[4][4];          // A rows for my 4 columns: 64 VGPRs, reused 64x
#pragma unroll
    for (int j = 0; j < 4; ++j)
#pragma unroll
      for (int q = 0; q < 4; ++q)
        a[j][q] =
            *reinterpret_cast<const float4*>(matA + (c0 + j) * RANK + q * 4);

    float* op = out + row0 * D_EMBED + c0;
    for (int row = 0; row < TILE_ROWS; ++row) {
      // wave-uniform address -> broadcast ds_read_b128 x4
      const float4* hv = reinterpret_cast<const float4*>(hr[row]);
      const float4 h0 = hv[0], h1 = hv[1], h2 = hv[2], h3 = hv[3];
      float4 o;
      o.x = dot4(h0, a[0][0]) + dot4(h1, a[0][1]) + dot4(h2, a[0][2]) +
            dot4(h3, a[0][3]);
      o.y = dot4(h0, a[1][0]) + dot4(h1, a[1][1]) + dot4(h2, a[1][2]) +
            dot4(h3, a[1][3]);
      o.z = dot4(h0, a[2][0]) + dot4(h1, a[2][1]) + dot4(h2, a[2][2]) +
            dot4(h3, a[2][3]);
      o.w = dot4(h0, a[3][0]) + dot4(h1, a[3][1]) + dot4(h2, a[3][2]) +
            dot4(h3, a[3][3]);
      *reinterpret_cast<float4*>(op + (long)row * D_EMBED) = o;
    }
  }
}

extern "C" void kernel_launch(void* const* d_in, const int* in_sizes, int n_in,
                              void* d_out, int out_size, void* d_ws,
                              size_t ws_size, hipStream_t stream) {
  const float* h    = (const float*)d_in[0];
  const float* matA = (const float*)d_in[1];
  const float* matB = (const float*)d_in[2];
  float* out        = (float*)d_out;

  const long M = (long)in_sizes[0] / D_EMBED;   // 16384 rows
  const int nblocks = (int)(M / TILE_ROWS);     // 256 blocks, ~1 per CU
  hipLaunchKernelGGL(lora_fused_kernel, dim3(nblocks), dim3(1024), 0, stream,
                     h, matA, matB, out);
}

// Round 3
// 131.441 us; speedup vs baseline: 3.3751x; 3.3751x over previous
//
#include <hip/hip_runtime.h>

// LoRA forward: out = (h @ B^T) @ A^T, h: (16384, 4096) f32, rank 16.
// R3 = R2 with the nontemporal-store type fixed (native clang vector type).
// Design: LDS-staged h (64-KB chunks, double-buffered, global_load_lds w=16,
// pre-swizzled source -> XOR-deswizzled ds_read_b128), counted vmcnt + raw
// s_barrier pipeline, wave-uniform B (scalar loads), nontemporal out stores.

constexpr int D_EMBED = 4096;
constexpr int RANK    = 16;
constexpr int ROWS    = 64;               // rows per block
constexpr int NWAVES  = 16;               // 1024 threads
constexpr int CHUNK   = 256;              // floats of d per chunk (1 KB/row)
constexpr int NCH     = D_EMBED / CHUNK;  // 16

typedef float f32x4 __attribute__((ext_vector_type(4)));

__device__ __forceinline__ void gload_lds16(const float* src, float* ldsdst) {
  __builtin_amdgcn_global_load_lds(
      (const __attribute__((address_space(1))) void*)src,
      (__attribute__((address_space(3))) void*)ldsdst, 16, 0, 0);
}

__device__ __forceinline__ float dot4(float4 a, float4 b) {
  return a.x * b.x + a.y * b.y + a.z * b.z + a.w * b.w;
}

__global__ __launch_bounds__(1024) void lora_kernel(
    const float* __restrict__ h,
    const float* __restrict__ matA,   // (D_EMBED, RANK) row-major
    const float* __restrict__ matB,   // (RANK, D_EMBED) row-major
    float* __restrict__ out) {
  // 128 KiB staging, double-buffered. After stage 1 the same memory is reused:
  //   hrp = [16 waves][16 r][64 rows] partials  (aliases sbuf[0], 64 KiB)
  //   hr  = [64 rows][16 r] reduced             (aliases sbuf[1] start, 4 KiB)
  __shared__ float sbuf[2][ROWS][CHUNK];
  float* const ldsbase = &sbuf[0][0][0];
  float(*const hrp)[RANK][ROWS] =
      reinterpret_cast<float(*)[RANK][ROWS]>(ldsbase);
  float(*const hr)[RANK] =
      reinterpret_cast<float(*)[RANK]>(ldsbase + ROWS * CHUNK);

  const int tid = threadIdx.x;
  const int w   = __builtin_amdgcn_readfirstlane(tid >> 6);  // wave id 0..15
  const int l   = tid & 63;                                  // lane id
  const long row0 = (long)blockIdx.x * ROWS;

  // ---- stage: issue 4 global_load_lds (rows 4w..4w+3) for chunk k -> buf b
  auto STAGE = [&](int b, int k) {
#pragma unroll
    for (int j = 0; j < 4; ++j) {
      const int R = w * 4 + j;
      // LDS dest is linear (base + lane*16); swizzle lives in the SOURCE:
      // LDS[R][slot l] <- h[R][slot l ^ (R&15)]  (float4 slots, 16 B each)
      const float* src =
          h + (row0 + R) * D_EMBED + (long)k * CHUNK + ((l ^ (R & 15)) * 4);
      gload_lds16(src, &sbuf[b][R][0]);
    }
  };

  float acc[RANK];
#pragma unroll
  for (int r = 0; r < RANK; ++r) acc[r] = 0.f;

  STAGE(0, 0);
  for (int k = 0; k < NCH; ++k) {
    if (k + 1 < NCH) {
      STAGE((k + 1) & 1, k + 1);
      // own chunk-k loads complete; the 4 chunk-(k+1) loads stay in flight
      asm volatile("s_waitcnt vmcnt(4)" ::: "memory");
    } else {
      asm volatile("s_waitcnt vmcnt(0)" ::: "memory");
    }
    __builtin_amdgcn_s_barrier();          // all waves' chunk-k loads landed
    __builtin_amdgcn_sched_barrier(0);
    asm volatile("" ::: "memory");

    // compute: thread (w,l) owns (row l, d-slice w): cols [w*16, w*16+16)
    const float4* hrow =
        reinterpret_cast<const float4*>(&sbuf[k & 1][l][0]);
    const long bofs = (long)k * CHUNK + w * 16;
#pragma unroll
    for (int q = 0; q < 4; ++q) {
      const float4 h4 = hrow[(w * 4 + q) ^ (l & 15)];  // deswizzle
#pragma unroll
      for (int r = 0; r < RANK; ++r) {
        // wave-uniform address -> scalar load (B never touches VMEM pipe)
        const float4 b4 = *reinterpret_cast<const float4*>(
            matB + (long)r * D_EMBED + bofs + q * 4);
        acc[r] += dot4(h4, b4);
      }
    }
    asm volatile("" ::: "memory");
    __builtin_amdgcn_s_barrier();          // computes done before overwrite
    __builtin_amdgcn_sched_barrier(0);
  }

  // ---- write partials (all staging loads drained; sbuf reusable) ----------
#pragma unroll
  for (int r = 0; r < RANK; ++r) hrp[w][r][l] = acc[r];  // lanes stride-1
  __syncthreads();

  // ---- reduce 16 wave-partials: thread (w,l) -> (row l, rank w) -----------
  {
    float s = 0.f;
#pragma unroll
    for (int w2 = 0; w2 < NWAVES; ++w2) s += hrp[w2][w][l];  // stride-1 lanes
    hr[l][w] = s;  // one-time write, conflict cost negligible
  }
  __syncthreads();

  // ---- stage 2: out[row][c] = sum_r hr[row][r] * A[c][r] ------------------
  {
    const int c0 = tid * 4;  // 4 contiguous cols; block covers 4096
    float4 a[4][4];          // A rows for my 4 cols, reused 64x
#pragma unroll
    for (int j = 0; j < 4; ++j)
#pragma unroll
      for (int q = 0; q < 4; ++q)
        a[j][q] = *reinterpret_cast<const float4*>(
            matA + (long)(c0 + j) * RANK + q * 4);

    float* op = out + row0 * D_EMBED + c0;
    for (int row = 0; row < ROWS; ++row) {
      const float4* hv = reinterpret_cast<const float4*>(hr[row]);  // bcast
      const float4 h0 = hv[0], h1 = hv[1], h2 = hv[2], h3 = hv[3];
      f32x4 o;
      o.x = dot4(h0, a[0][0]) + dot4(h1, a[0][1]) + dot4(h2, a[0][2]) +
            dot4(h3, a[0][3]);
      o.y = dot4(h0, a[1][0]) + dot4(h1, a[1][1]) + dot4(h2, a[1][2]) +
            dot4(h3, a[1][3]);
      o.z = dot4(h0, a[2][0]) + dot4(h1, a[2][1]) + dot4(h2, a[2][2]) +
            dot4(h3, a[2][3]);
      o.w = dot4(h0, a[3][0]) + dot4(h1, a[3][1]) + dot4(h2, a[3][2]) +
            dot4(h3, a[3][3]);
      __builtin_nontemporal_store(
          o, reinterpret_cast<f32x4*>(op + (long)row * D_EMBED));
    }
  }
}

extern "C" void kernel_launch(void* const* d_in, const int* in_sizes, int n_in,
                              void* d_out, int out_size, void* d_ws,
                              size_t ws_size, hipStream_t stream) {
  const float* h    = (const float*)d_in[0];
  const float* matA = (const float*)d_in[1];
  const float* matB = (const float*)d_in[2];
  float* out        = (float*)d_out;

  const long M = (long)in_sizes[0] / D_EMBED;  // 16384 rows
  const int nblocks = (int)(M / ROWS);         // 256 blocks, ~1 per CU
  hipLaunchKernelGGL(lora_kernel, dim3(nblocks), dim3(1024), 0, stream,
                     h, matA, matB, out);
}